// Round 3
// baseline (4157.471 us; speedup 1.0000x reference)
//
#include <hip/hip_runtime.h>
#include <math.h>

#define B_SZ 2
#define T_SEQ 2048
#define D_MODEL 2048
#define NHEAD 16
#define HDIM 128
#define FFN 8192
#define NTOK (B_SZ*T_SEQ)   // 4096

// d_out layout (fp32): x_posterior | tpn_loss | causal_loss | g | binary | probs
#define OFF_TPN 8388608
#define OFF_CL  8388609
#define OFF_G   8388610
#define OFF_B   8392706
#define OFF_CP  8396802

#define RLO 1024.0f
#define RLOI 9.765625e-4f   // 1/1024

typedef __attribute__((ext_vector_type(8))) _Float16 f16x8;
typedef __attribute__((ext_vector_type(4))) float f32x4;

__device__ __forceinline__ f16x8 ld8h(const _Float16* p) {
  return *reinterpret_cast<const f16x8*>(p);
}
__device__ __forceinline__ f32x4 mfma16h(f16x8 a, f16x8 b, f32x4 c) {
  return __builtin_amdgcn_mfma_f32_16x16x32_f16(a, b, c, 0, 0, 0);
}
__device__ __forceinline__ f32x4 zero4() { f32x4 z = {0.f,0.f,0.f,0.f}; return z; }
__device__ __forceinline__ float wredsum(float v) {
  #pragma unroll
  for (int d = 1; d < 64; d <<= 1) v += __shfl_xor(v, d, 64);
  return v;
}
__device__ __forceinline__ void split1(float v, _Float16& h, _Float16& l) {
  _Float16 hh = (_Float16)v;
  h = hh;
  l = (_Float16)((v - (float)hh) * RLO);
}
__device__ __forceinline__ void split8(const float* f, f16x8& h, f16x8& l) {
  #pragma unroll
  for (int i = 0; i < 8; ++i) {
    _Float16 hh = (_Float16)f[i];
    h[i] = hh;
    l[i] = (_Float16)((f[i] - (float)hh) * RLO);
  }
}

// ---- RMSNorm: fp32 in -> fp32 out, one row per block ----
__global__ __launch_bounds__(256) void rmsnorm_kernel(const float* __restrict__ x,
                                                      const float* __restrict__ wgt,
                                                      float* __restrict__ out) {
  const int row = blockIdx.x, tid = threadIdx.x;
  const float* xr = x + (size_t)row * D_MODEL;
  float4 v0 = *(const float4*)(xr + tid*8);
  float4 v1 = *(const float4*)(xr + tid*8 + 4);
  float ss = v0.x*v0.x + v0.y*v0.y + v0.z*v0.z + v0.w*v0.w
           + v1.x*v1.x + v1.y*v1.y + v1.z*v1.z + v1.w*v1.w;
  ss = wredsum(ss);
  __shared__ float red[4];
  if ((tid & 63) == 0) red[tid >> 6] = ss;
  __syncthreads();
  float tot = red[0] + red[1] + red[2] + red[3];
  float inv = 1.f / sqrtf(tot / (float)D_MODEL + 1e-6f);
  float4 w0 = *(const float4*)(wgt + tid*8);
  float4 w1 = *(const float4*)(wgt + tid*8 + 4);
  float* o = out + (size_t)row * D_MODEL + tid*8;
  float4 o0, o1;
  o0.x = v0.x*inv*w0.x; o0.y = v0.y*inv*w0.y; o0.z = v0.z*inv*w0.z; o0.w = v0.w*inv*w0.w;
  o1.x = v1.x*inv*w1.x; o1.y = v1.y*inv*w1.y; o1.z = v1.z*inv*w1.z; o1.w = v1.w*inv*w1.w;
  *(float4*)o = o0; *(float4*)(o + 4) = o1;
}

// ---- split-precision GEMM: C[M][N] = A[M][K] @ B[K][N] (B fp32 k-major) ----
// A source: fp32 (split on stage) or pre-split f16 pair (ASPLIT).
// B staged with on-the-fly transpose+split: thread owns one column, 16
// lane-coalesced dword loads, 4 aligned b128 LDS writes.
// 128x128 tile, BK=32, 4 waves in 2x2 of 64x64, 3x mfma_f32_16x16x32_f16.
// MODE: 0 plain, 1 +bias, 2 silu(v+bias), 3 +resid, 4 silu(g)*v (g split pair)
template<int MODE, bool OUT_SPLIT, bool ASPLIT>
__global__ __launch_bounds__(256) void gemm_kernel(
    const float* __restrict__ A,
    const _Float16* __restrict__ Ahi, const _Float16* __restrict__ Alo,
    const float* __restrict__ Bw,
    const float* __restrict__ bias, const float* __restrict__ resid,
    const _Float16* __restrict__ ghi, const _Float16* __restrict__ glo,
    void* __restrict__ C1, void* __restrict__ C2,
    int M, int N, int K) {
  const int n0 = blockIdx.x * 128;
  const int m0 = blockIdx.y * 128;
  const int tid = threadIdx.x;
  const int lane = tid & 63;
  const int w = tid >> 6;
  const int wr = w >> 1, wc = w & 1;
  const int l16 = lane & 15, lg = lane >> 4;
  __shared__ _Float16 Ah[128][40];   // +8 pad on 32-elem rows
  __shared__ _Float16 Al[128][40];
  __shared__ _Float16 Bh[128][40];   // [n][k]
  __shared__ _Float16 Bl[128][40];
  f32x4 acc1[4][4], acc2[4][4];
  #pragma unroll
  for (int i = 0; i < 4; ++i)
    #pragma unroll
    for (int j = 0; j < 4; ++j) { acc1[i][j] = zero4(); acc2[i][j] = zero4(); }
  const int srow = tid >> 1, skc = (tid & 1) * 16;
  const float*    Ap  = ASPLIT ? nullptr : (A + (size_t)(m0 + srow) * K + skc);
  const _Float16* Aph = ASPLIT ? (Ahi + (size_t)(m0 + srow) * K + skc) : nullptr;
  const _Float16* Apl = ASPLIT ? (Alo + (size_t)(m0 + srow) * K + skc) : nullptr;
  const int bn = tid & 127;          // owned B column within tile
  const int bk0 = (tid >> 7) * 16;   // k half: 0 or 16
  const float* Bp = Bw + (size_t)bk0 * N + n0 + bn;
  for (int kk = 0; kk < K; kk += 32) {
    __syncthreads();
    // A tile
    f16x8 ah0, al0, ah1, al1;
    if (ASPLIT) {
      ah0 = *(const f16x8*)(Aph + kk);
      ah1 = *(const f16x8*)(Aph + kk + 8);
      al0 = *(const f16x8*)(Apl + kk);
      al1 = *(const f16x8*)(Apl + kk + 8);
    } else {
      float fa[16];
      *(float4*)(fa)      = *(const float4*)(Ap + kk);
      *(float4*)(fa + 4)  = *(const float4*)(Ap + kk + 4);
      *(float4*)(fa + 8)  = *(const float4*)(Ap + kk + 8);
      *(float4*)(fa + 12) = *(const float4*)(Ap + kk + 12);
      split8(fa, ah0, al0);
      split8(fa + 8, ah1, al1);
    }
    // B tile: rows kk+bk0..+15, column n0+bn  (lane-coalesced down the column)
    float fb[16];
    {
      const float* bp = Bp + (size_t)kk * N;
      #pragma unroll
      for (int j = 0; j < 16; ++j) fb[j] = bp[(size_t)j * N];
    }
    f16x8 bh0, bl0, bh1, bl1;
    split8(fb, bh0, bl0);
    split8(fb + 8, bh1, bl1);
    *(f16x8*)&Ah[srow][skc]     = ah0;
    *(f16x8*)&Ah[srow][skc + 8] = ah1;
    *(f16x8*)&Al[srow][skc]     = al0;
    *(f16x8*)&Al[srow][skc + 8] = al1;
    *(f16x8*)&Bh[bn][bk0]       = bh0;
    *(f16x8*)&Bh[bn][bk0 + 8]   = bh1;
    *(f16x8*)&Bl[bn][bk0]       = bl0;
    *(f16x8*)&Bl[bn][bk0 + 8]   = bl1;
    __syncthreads();
    f16x8 af_h[4], af_l[4];
    #pragma unroll
    for (int i = 0; i < 4; ++i) {
      af_h[i] = ld8h(&Ah[wr*64 + i*16 + l16][lg*8]);
      af_l[i] = ld8h(&Al[wr*64 + i*16 + l16][lg*8]);
    }
    #pragma unroll
    for (int j = 0; j < 4; ++j) {
      f16x8 bh = ld8h(&Bh[wc*64 + j*16 + l16][lg*8]);
      f16x8 bl = ld8h(&Bl[wc*64 + j*16 + l16][lg*8]);
      #pragma unroll
      for (int i = 0; i < 4; ++i) {
        acc1[i][j] = mfma16h(af_h[i], bh, acc1[i][j]);
        acc2[i][j] = mfma16h(af_h[i], bl, acc2[i][j]);
        acc2[i][j] = mfma16h(af_l[i], bh, acc2[i][j]);
      }
    }
  }
  #pragma unroll
  for (int i = 0; i < 4; ++i) {
    const int row0 = m0 + wr*64 + i*16 + lg*4;   // D layout: row=(lane>>4)*4+t, col=lane&15
    #pragma unroll
    for (int j = 0; j < 4; ++j) {
      const int col = n0 + wc*64 + j*16 + l16;
      float bv = (MODE == 1 || MODE == 2) ? bias[col] : 0.f;
      #pragma unroll
      for (int t = 0; t < 4; ++t) {
        const size_t idx = (size_t)(row0 + t) * N + col;
        float v = acc1[i][j][t] + acc2[i][j][t] * RLOI + bv;
        if (MODE == 2) v = v / (1.f + expf(-v));
        if (MODE == 3) v += resid[idx];
        if (MODE == 4) {
          float g = (float)ghi[idx] + (float)glo[idx] * RLOI;
          v = g / (1.f + expf(-g)) * v;
        }
        if (OUT_SPLIT) {
          _Float16 h, l; split1(v, h, l);
          ((_Float16*)C1)[idx] = h;
          ((_Float16*)C2)[idx] = l;
        } else {
          ((float*)C1)[idx] = v;
        }
      }
    }
  }
}

// ---- RoPE (neox), in place on fp32 Q,K; one token-row per block ----
__global__ __launch_bounds__(256) void rope_kernel(float* __restrict__ Q,
                                                   float* __restrict__ K) {
  const int row = blockIdx.x;
  const int tpos = row & (T_SEQ - 1);
  __shared__ float svs[64], cvs[64];
  if (threadIdx.x < 64) {
    double invf = exp(-(double)threadIdx.x * (9.210340371976184 / 64.0));
    double ph = fmod((double)tpos * invf, 6.283185307179586476925);
    sincosf((float)ph, &svs[threadIdx.x], &cvs[threadIdx.x]);
  }
  __syncthreads();
  for (int item = threadIdx.x; item < NHEAD * 64; item += 256) {
    const int h = item >> 6, d = item & 63;
    const float sv = svs[d], cv = cvs[d];
    const size_t i0 = (size_t)row * D_MODEL + h*HDIM + d;
    const size_t i1 = i0 + 64;
    float q0 = Q[i0], q1 = Q[i1];
    Q[i0] = q0*cv - q1*sv;
    Q[i1] = q1*cv + q0*sv;
    float k0 = K[i0], k1 = K[i1];
    K[i0] = k0*cv - k1*sv;
    K[i1] = k1*cv + k0*sv;
  }
}

// ---- flash attention, split precision: 64 q-rows/block, KV tiles of 32 ----
__global__ __launch_bounds__(256) void attn_kernel(const float* __restrict__ Qg,
                                                   const float* __restrict__ Kg,
                                                   const float* __restrict__ Vg,
                                                   float* __restrict__ Og) {
  const int qb = blockIdx.x;
  const int bh = blockIdx.y;
  const int b = bh >> 4, h = bh & 15;
  const int tid = threadIdx.x, lane = tid & 63, w = tid >> 6;
  const int l16 = lane & 15, lg = lane >> 4;
  __shared__ _Float16 Ksh[32][136], Ksl[32][136];
  __shared__ _Float16 Vth[128][40], Vtl[128][40];
  __shared__ _Float16 Psh[4][16][40], Psl[4][16][40];
  const size_t hbase = (size_t)b * T_SEQ * D_MODEL + (size_t)h * HDIM;
  const size_t qrow0 = (size_t)qb * 64;

  f16x8 qf_h[4], qf_l[4];
  {
    const float* qp = Qg + hbase + (qrow0 + w*16 + l16) * D_MODEL + lg*8;
    #pragma unroll
    for (int c = 0; c < 4; ++c) {
      float f[8];
      *(float4*)(f)     = *(const float4*)(qp + c*32);
      *(float4*)(f + 4) = *(const float4*)(qp + c*32 + 4);
      split8(f, qf_h[c], qf_l[c]);
    }
  }
  f32x4 acc1[8], acc2[8];
  #pragma unroll
  for (int df = 0; df < 8; ++df) { acc1[df] = zero4(); acc2[df] = zero4(); }
  float mrow[4] = {-3e38f,-3e38f,-3e38f,-3e38f};
  float drow[4] = {0.f,0.f,0.f,0.f};

  const int nkb = (qb + 1) * 2;
  const int kvr = tid >> 3, dch = (tid & 7) * 16;
  const float scale = 0.088388347648318447f;  // 1/sqrt(128)

  for (int kb = 0; kb < nkb; ++kb) {
    __syncthreads();
    {
      const float* kp = Kg + hbase + (size_t)(kb*32 + kvr) * D_MODEL + dch;
      float f[16];
      *(float4*)(f)      = *(const float4*)(kp);
      *(float4*)(f + 4)  = *(const float4*)(kp + 4);
      *(float4*)(f + 8)  = *(const float4*)(kp + 8);
      *(float4*)(f + 12) = *(const float4*)(kp + 12);
      f16x8 h0, l0, h1, l1;
      split8(f, h0, l0); split8(f + 8, h1, l1);
      *(f16x8*)&Ksh[kvr][dch]     = h0;
      *(f16x8*)&Ksh[kvr][dch + 8] = h1;
      *(f16x8*)&Ksl[kvr][dch]     = l0;
      *(f16x8*)&Ksl[kvr][dch + 8] = l1;
      const float* vp = Vg + hbase + (size_t)(kb*32 + kvr) * D_MODEL + dch;
      *(float4*)(f)      = *(const float4*)(vp);
      *(float4*)(f + 4)  = *(const float4*)(vp + 4);
      *(float4*)(f + 8)  = *(const float4*)(vp + 8);
      *(float4*)(f + 12) = *(const float4*)(vp + 12);
      #pragma unroll
      for (int i = 0; i < 16; ++i) {
        _Float16 hh, ll; split1(f[i], hh, ll);
        Vth[dch + i][kvr] = hh;
        Vtl[dch + i][kvr] = ll;
      }
    }
    __syncthreads();

    f32x4 s0 = zero4(), s0x = zero4(), s1 = zero4(), s1x = zero4();
    #pragma unroll
    for (int c = 0; c < 4; ++c) {
      f16x8 kh0 = ld8h(&Ksh[l16][c*32 + lg*8]);
      f16x8 kl0 = ld8h(&Ksl[l16][c*32 + lg*8]);
      f16x8 kh1 = ld8h(&Ksh[16 + l16][c*32 + lg*8]);
      f16x8 kl1 = ld8h(&Ksl[16 + l16][c*32 + lg*8]);
      s0  = mfma16h(qf_h[c], kh0, s0);
      s0x = mfma16h(qf_h[c], kl0, s0x);
      s0x = mfma16h(qf_l[c], kh0, s0x);
      s1  = mfma16h(qf_h[c], kh1, s1);
      s1x = mfma16h(qf_h[c], kl1, s1x);
      s1x = mfma16h(qf_l[c], kh1, s1x);
    }

    float p0[4], p1[4], corrv[4];
    #pragma unroll
    for (int t = 0; t < 4; ++t) {
      int qrow = qb*64 + w*16 + lg*4 + t;
      float a  = (s0[t] + s0x[t] * RLOI) * scale;
      float bb = (s1[t] + s1x[t] * RLOI) * scale;
      if (kb*32      + l16 > qrow) a  = -1e9f;
      if (kb*32 + 16 + l16 > qrow) bb = -1e9f;
      float mx = fmaxf(a, bb);
      #pragma unroll
      for (int d = 1; d < 16; d <<= 1) mx = fmaxf(mx, __shfl_xor(mx, d, 64));
      float mnew = fmaxf(mrow[t], mx);
      float corr = expf(mrow[t] - mnew);
      float e0 = expf(a - mnew), e1 = expf(bb - mnew);
      float ps = e0 + e1;
      #pragma unroll
      for (int d = 1; d < 16; d <<= 1) ps += __shfl_xor(ps, d, 64);
      drow[t] = drow[t] * corr + ps;
      mrow[t] = mnew;
      corrv[t] = corr;
      p0[t] = e0; p1[t] = e1;
    }
    #pragma unroll
    for (int df = 0; df < 8; ++df)
      #pragma unroll
      for (int t = 0; t < 4; ++t) { acc1[df][t] *= corrv[t]; acc2[df][t] *= corrv[t]; }

    // P (D-layout) -> per-wave LDS -> reload in A-frag layout (split pair).
    #pragma unroll
    for (int t = 0; t < 4; ++t) {
      _Float16 hh, ll;
      split1(p0[t], hh, ll);
      Psh[w][lg*4 + t][l16] = hh;  Psl[w][lg*4 + t][l16] = ll;
      split1(p1[t], hh, ll);
      Psh[w][lg*4 + t][16 + l16] = hh;  Psl[w][lg*4 + t][16 + l16] = ll;
    }
    asm volatile("s_waitcnt lgkmcnt(0)" ::: "memory");
    __builtin_amdgcn_sched_barrier(0);
    f16x8 pf_h = ld8h(&Psh[w][l16][lg*8]);
    f16x8 pf_l = ld8h(&Psl[w][l16][lg*8]);
    #pragma unroll
    for (int df = 0; df < 8; ++df) {
      f16x8 vh = ld8h(&Vth[df*16 + l16][lg*8]);
      f16x8 vl = ld8h(&Vtl[df*16 + l16][lg*8]);
      acc1[df] = mfma16h(pf_h, vh, acc1[df]);
      acc2[df] = mfma16h(pf_h, vl, acc2[df]);
      acc2[df] = mfma16h(pf_l, vh, acc2[df]);
    }
  }
  #pragma unroll
  for (int df = 0; df < 8; ++df)
    #pragma unroll
    for (int t = 0; t < 4; ++t) {
      float o = (acc1[df][t] + acc2[df][t] * RLOI) / drow[t];
      Og[hbase + (qrow0 + w*16 + lg*4 + t) * D_MODEL + df*16 + l16] = o;
    }
}

// ---- prev[b,t,:] = t==0 ? 0 : x_post[b,t-1,:] (fp32) ----
__global__ __launch_bounds__(256) void shiftprev_kernel(const float* __restrict__ xpost,
                                                        float* __restrict__ prev) {
  const int row = blockIdx.x;
  const int tpos = row & (T_SEQ - 1);
  const size_t o = (size_t)row * D_MODEL + threadIdx.x * 8;
  float4 z = {0.f,0.f,0.f,0.f};
  if (tpos == 0) {
    *(float4*)(prev + o) = z;
    *(float4*)(prev + o + 4) = z;
  } else {
    *(float4*)(prev + o)     = *(const float4*)(xpost + o - D_MODEL);
    *(float4*)(prev + o + 4) = *(const float4*)(xpost + o - D_MODEL + 4);
  }
}

// ---- per-row err = mean_D (pred - (xpost - xorig))^2 ----
__global__ __launch_bounds__(256) void err_kernel(const float* __restrict__ pred,
                                                  const float* __restrict__ xpost,
                                                  const float* __restrict__ xorig,
                                                  float* __restrict__ err) {
  const int row = blockIdx.x, tid = threadIdx.x;
  const size_t base = (size_t)row * D_MODEL + tid * 8;
  const float* pp = pred + base;
  const float* ap = xpost + base;
  const float* op = xorig + base;
  float ss = 0.f;
  #pragma unroll
  for (int i = 0; i < 8; ++i) {
    float d = pp[i] - (ap[i] - op[i]);
    ss += d * d;
  }
  ss = wredsum(ss);
  __shared__ float red[4];
  if ((tid & 63) == 0) red[tid >> 6] = ss;
  __syncthreads();
  if (tid == 0) err[row] = (red[0]+red[1]+red[2]+red[3]) / (float)D_MODEL;
}

// ---- stats: mean/std of err -> tpn_loss, g_continuous, binary_targets ----
__global__ __launch_bounds__(1024) void stats_kernel(const float* __restrict__ err,
                                                     float* __restrict__ dout) {
  __shared__ float red[16];
  __shared__ float sh[2];
  const int tid = threadIdx.x;
  float s = 0.f;
  for (int i = tid; i < NTOK; i += 1024) s += err[i];
  s = wredsum(s);
  if ((tid & 63) == 0) red[tid >> 6] = s;
  __syncthreads();
  if (tid == 0) {
    float t = 0.f;
    for (int i = 0; i < 16; ++i) t += red[i];
    sh[0] = t / (float)NTOK;
  }
  __syncthreads();
  const float mean = sh[0];
  float v = 0.f;
  for (int i = tid; i < NTOK; i += 1024) { float d = err[i] - mean; v += d * d; }
  v = wredsum(v);
  __syncthreads();
  if ((tid & 63) == 0) red[tid >> 6] = v;
  __syncthreads();
  if (tid == 0) {
    float t = 0.f;
    for (int i = 0; i < 16; ++i) t += red[i];
    sh[1] = sqrtf(t / (float)NTOK);
    dout[OFF_TPN] = mean;   // tpn_loss == mean(err)
  }
  __syncthreads();
  const float stdv = sh[1];
  for (int i = tid; i < NTOK; i += 1024) {
    float z = (err[i] - mean) / (stdv + 1e-6f);
    dout[OFF_G + i] = 1.f / (1.f + expf(-z));
    dout[OFF_B + i] = (err[i] > mean) ? 1.f : 0.f;
  }
}

// ---- causal router scores/probs ----
__global__ __launch_bounds__(256) void cscore_kernel(const float* __restrict__ x,
                                                     const float* __restrict__ rwv,
                                                     const float* __restrict__ rbv,
                                                     float* __restrict__ cs,
                                                     float* __restrict__ probs) {
  const int row = blockIdx.x, tid = threadIdx.x;
  const float* xr = x + (size_t)row * D_MODEL + tid * 8;
  const float* wr = rwv + tid * 8;
  float s = 0.f;
  #pragma unroll
  for (int i = 0; i < 8; ++i) s += xr[i] * wr[i];
  s = wredsum(s);
  __shared__ float red[4];
  if ((tid & 63) == 0) red[tid >> 6] = s;
  __syncthreads();
  if (tid == 0) {
    float v = red[0]+red[1]+red[2]+red[3] + rbv[0];
    cs[row] = v;
    probs[row] = 1.f / (1.f + expf(-v));
  }
}

// ---- BCE-with-logits ----
__global__ __launch_bounds__(1024) void closs_kernel(const float* __restrict__ cs,
                                                     const float* __restrict__ tgt,
                                                     float* __restrict__ outv) {
  __shared__ float red[16];
  const int tid = threadIdx.x;
  float a = 0.f;
  for (int i = tid; i < NTOK; i += 1024) {
    float s = cs[i], t = tgt[i];
    a += fmaxf(s, 0.f) - s * t + log1pf(expf(-fabsf(s)));
  }
  a = wredsum(a);
  if ((tid & 63) == 0) red[tid >> 6] = a;
  __syncthreads();
  if (tid == 0) {
    float t = 0.f;
    for (int i = 0; i < 16; ++i) t += red[i];
    outv[0] = t / (float)NTOK;
  }
}

extern "C" void kernel_launch(void* const* d_in, const int* in_sizes, int n_in,
                              void* d_out, int out_size, void* d_ws, size_t ws_size,
                              hipStream_t stream) {
  (void)in_sizes; (void)n_in; (void)out_size; (void)ws_size;
  const float* x_in = (const float*)d_in[0];
  const float* q_w  = (const float*)d_in[1];
  const float* q_b  = (const float*)d_in[2];
  const float* k_w  = (const float*)d_in[3];
  const float* k_b  = (const float*)d_in[4];
  const float* v_w  = (const float*)d_in[5];
  const float* v_b  = (const float*)d_in[6];
  const float* o_w  = (const float*)d_in[7];
  const float* ln1  = (const float*)d_in[8];
  const float* ln2  = (const float*)d_in[9];
  const float* gw   = (const float*)d_in[10];
  const float* uw   = (const float*)d_in[11];
  const float* dw   = (const float*)d_in[12];
  const float* t1w  = (const float*)d_in[13];
  const float* t1b  = (const float*)d_in[14];
  const float* t2w  = (const float*)d_in[15];
  const float* t2b  = (const float*)d_in[16];
  const float* rw   = (const float*)d_in[17];
  const float* rb   = (const float*)d_in[18];
  float* out = (float*)d_out;
  char* ws = (char*)d_ws;

  // workspace layout (bytes), total < 202 MB, all regions disjoint in time:
  // R0 [0,33554432):        Hf(ln1) -> CTX(attn) -> Hf(ln2) -> PREV
  // R1 [33554432,67108864): Qf -> Xf
  // R2 [67108864,134217728):   Kf; later mlp_hi (67MB, spans R2+R3); later A1(hi half), PRED uses R3
  // R3 [100663296,134217728):  Vf (inside mlp_hi span)
  // R4 [134217728,201326592):  mlp_lo (67MB)
  // ERR [201326592), CS [201342976)
  float* Hf   = (float*)(ws + 0);            // R0
  float* CTX  = (float*)(ws + 0);            // R0
  float* PREV = (float*)(ws + 0);            // R0
  float* Qf   = (float*)(ws + 33554432);     // R1
  float* Xf   = (float*)(ws + 33554432);     // R1
  float* Kf   = (float*)(ws + 67108864);     // R2
  float* Vf   = (float*)(ws + 100663296);    // R3
  _Float16* MLPh = (_Float16*)(ws + 67108864);   // R2+R3 span (67MB)
  _Float16* MLPl = (_Float16*)(ws + 134217728);  // R4 (67MB)
  float* A1f   = (float*)(ws + 67108864);    // R2 (after mlp dead)
  float* PREDf = (float*)(ws + 100663296);   // R3 (after mlp dead)
  float* ERRf  = (float*)(ws + 201326592);
  float* CSf   = (float*)(ws + 201342976);

  rmsnorm_kernel<<<NTOK, 256, 0, stream>>>(x_in, ln1, Hf);

  gemm_kernel<1,false,false><<<dim3(16,32),256,0,stream>>>(Hf, nullptr, nullptr, q_w, q_b, nullptr, nullptr, nullptr, Qf, nullptr, NTOK, D_MODEL, D_MODEL);
  gemm_kernel<1,false,false><<<dim3(16,32),256,0,stream>>>(Hf, nullptr, nullptr, k_w, k_b, nullptr, nullptr, nullptr, Kf, nullptr, NTOK, D_MODEL, D_MODEL);
  gemm_kernel<1,false,false><<<dim3(16,32),256,0,stream>>>(Hf, nullptr, nullptr, v_w, v_b, nullptr, nullptr, nullptr, Vf, nullptr, NTOK, D_MODEL, D_MODEL);

  rope_kernel<<<NTOK, 256, 0, stream>>>(Qf, Kf);
  attn_kernel<<<dim3(T_SEQ/64, B_SZ*NHEAD), 256, 0, stream>>>(Qf, Kf, Vf, CTX);

  // x = hidden + ctx @ o_w -> Xf (R1; Qf dead)
  gemm_kernel<3,false,false><<<dim3(16,32),256,0,stream>>>(CTX, nullptr, nullptr, o_w, nullptr, x_in, nullptr, nullptr, Xf, nullptr, NTOK, D_MODEL, D_MODEL);

  rmsnorm_kernel<<<NTOK, 256, 0, stream>>>(Xf, ln2, Hf);

  // gate -> split pair (K/V regions dead after attention)
  gemm_kernel<0,true,false><<<dim3(64,32),256,0,stream>>>(Hf, nullptr, nullptr, gw, nullptr, nullptr, nullptr, nullptr, MLPh, MLPl, NTOK, FFN, D_MODEL);
  // up + fused swiglu, in-place over gate pair -> mlp split pair
  gemm_kernel<4,true,false><<<dim3(64,32),256,0,stream>>>(Hf, nullptr, nullptr, uw, nullptr, nullptr, MLPh, MLPl, MLPh, MLPl, NTOK, FFN, D_MODEL);
  // x_posterior = x + mlp -> d_out (A = pre-split mlp pair)
  gemm_kernel<3,false,true><<<dim3(16,32),256,0,stream>>>(nullptr, MLPh, MLPl, dw, nullptr, Xf, nullptr, nullptr, out, nullptr, NTOK, D_MODEL, FFN);

  // TPN
  shiftprev_kernel<<<NTOK, 256, 0, stream>>>(out, PREV);
  gemm_kernel<2,false,false><<<dim3(16,32),256,0,stream>>>(PREV, nullptr, nullptr, t1w, t1b, nullptr, nullptr, nullptr, A1f, nullptr, NTOK, D_MODEL, D_MODEL);
  gemm_kernel<1,false,false><<<dim3(16,32),256,0,stream>>>(A1f, nullptr, nullptr, t2w, t2b, nullptr, nullptr, nullptr, PREDf, nullptr, NTOK, D_MODEL, D_MODEL);

  err_kernel<<<NTOK, 256, 0, stream>>>(PREDf, out, x_in, ERRf);
  stats_kernel<<<1, 1024, 0, stream>>>(ERRf, out);
  cscore_kernel<<<NTOK, 256, 0, stream>>>(x_in, rw, rb, CSf, out + OFF_CP);
  closs_kernel<<<1, 1024, 0, stream>>>(CSf, out + OFF_B, out + OFF_CL);
}